// Round 8
// baseline (283.726 us; speedup 1.0000x reference)
//
#include <hip/hip_runtime.h>
#include <math.h>

#define L_SEQ 2048
#define D_EMB 1024
#define NHEADS 16
#define HD 64
#define BHEADS 32   // N*NHEADS
#define NBATCH 2
#define LN_EPS 1e-5f
#define SCALING 0.125f

typedef __attribute__((ext_vector_type(8))) __bf16 bf16x8;
typedef __attribute__((ext_vector_type(4))) float f32x4;
typedef const __attribute__((address_space(1))) unsigned int* gptr_as1;
typedef __attribute__((address_space(3))) unsigned int* lptr_as3;

__device__ __forceinline__ void load16_to_lds(const void* g, void* l) {
  __builtin_amdgcn_global_load_lds((gptr_as1)g, (lptr_as3)l, 16, 0, 0);
}

__device__ __forceinline__ unsigned short f2bf(float f) {
  unsigned int u = __float_as_uint(f);
  u += 0x7fff + ((u >> 16) & 1);   // round-to-nearest-even
  return (unsigned short)(u >> 16);
}

__device__ __forceinline__ float bflo(unsigned int u) { return __uint_as_float(u << 16); }
__device__ __forceinline__ float bfhi(unsigned int u) { return __uint_as_float(u & 0xffff0000u); }
__device__ __forceinline__ float bf2f(unsigned short us) {
  return __uint_as_float((unsigned int)us << 16);
}

// ---------------- four-tensor fp32 -> bf16 convert ----------------
__global__ __launch_bounds__(256) void cvt4_bf16_kernel(
    const float* __restrict__ a, int na, const float* __restrict__ b, int nb,
    const float* __restrict__ c, int nc, const float* __restrict__ d, int nd,
    unsigned short* __restrict__ oa, unsigned short* __restrict__ ob,
    unsigned short* __restrict__ oc, unsigned short* __restrict__ od) {
  int i = (blockIdx.x * 256 + threadIdx.x) * 4;
  const float* src;
  unsigned short* dst;
  int j;
  if (i < na) { src = a; dst = oa; j = i; }
  else if (i < na + nb) { src = b; dst = ob; j = i - na; }
  else if (i < na + nb + nc) { src = c; dst = oc; j = i - na - nb; }
  else if (i < na + nb + nc + nd) { src = d; dst = od; j = i - na - nb - nc; }
  else return;
  float4 v = *(const float4*)&src[j];
  ushort4 o;
  o.x = f2bf(v.x); o.y = f2bf(v.y); o.z = f2bf(v.z); o.w = f2bf(v.w);
  *(ushort4*)&dst[j] = o;
}

// ---------------- q+v GEMM (k columns skipped!), 128x128, BK=32 ----------------
// cols [0,1024) -> q_bf row-major; cols [1024,2048) -> v, transposed into vT.
// W rows: q -> same col; v -> col + 1024 (skip k rows of W_in). Bias likewise.
__global__ __launch_bounds__(256) void gemm_qv(
    const unsigned short* __restrict__ A, const unsigned short* __restrict__ B,
    const float* __restrict__ bias, unsigned short* __restrict__ qbf,
    unsigned short* __restrict__ vT, int K) {
  __shared__ unsigned short As[4096];   // 128x32 bf16, fragment-major
  __shared__ unsigned short Bs[4096];
  // by-pair swizzle for B-tile L2 reuse
  const int id = blockIdx.y * 16 + blockIdx.x;    // grid (16, 32)
  const int by = (id >> 5) * 2 + (id & 1);
  const int bx = (id & 31) >> 1;
  const int bm = by * 128;
  const int bn = bx * 128;                        // [0,2048)
  const int woff = (bn < D_EMB) ? 0 : D_EMB;      // skip k rows for v tiles
  const int tid = threadIdx.x;
  const int lane = tid & 63;
  const int wave = tid >> 6;
  const int wr = (wave >> 1) * 64;
  const int wc = (wave & 1) * 64;

  const int c0 = tid, c1 = tid + 256;
  const unsigned short* ga0 = A + (size_t)(bm + (c0 >> 6) * 16 + (c0 & 15)) * K + ((c0 >> 4) & 3) * 8;
  const unsigned short* ga1 = A + (size_t)(bm + (c1 >> 6) * 16 + (c1 & 15)) * K + ((c1 >> 4) & 3) * 8;
  const unsigned short* gb0 = B + (size_t)(bn + woff + (c0 >> 6) * 16 + (c0 & 15)) * K + ((c0 >> 4) & 3) * 8;
  const unsigned short* gb1 = B + (size_t)(bn + woff + (c1 >> 6) * 16 + (c1 & 15)) * K + ((c1 >> 4) & 3) * 8;

  f32x4 acc[4][4] = {};
  for (int k0 = 0; k0 < K; k0 += 32) {
    load16_to_lds(ga0 + k0, &As[c0 * 8]);
    load16_to_lds(ga1 + k0, &As[c1 * 8]);
    load16_to_lds(gb0 + k0, &Bs[c0 * 8]);
    load16_to_lds(gb1 + k0, &Bs[c1 * 8]);
    __syncthreads();
    bf16x8 af[4], bf[4];
    #pragma unroll
    for (int i = 0; i < 4; ++i)
      af[i] = *(const bf16x8*)&As[((wr >> 4) + i) * 512 + lane * 8];
    #pragma unroll
    for (int j = 0; j < 4; ++j)
      bf[j] = *(const bf16x8*)&Bs[((wc >> 4) + j) * 512 + lane * 8];
    #pragma unroll
    for (int i = 0; i < 4; ++i)
      #pragma unroll
      for (int j = 0; j < 4; ++j)
        acc[i][j] = __builtin_amdgcn_mfma_f32_16x16x32_bf16(af[i], bf[j], acc[i][j], 0, 0, 0);
    __syncthreads();
  }
  const int lc = lane & 15;
  const int lr4 = (lane >> 4) << 2;
  float bv[4];
  #pragma unroll
  for (int j = 0; j < 4; ++j) bv[j] = bias[bn + woff + wc + j * 16 + lc];
  if (bn < D_EMB) {
    #pragma unroll
    for (int i = 0; i < 4; ++i)
      #pragma unroll
      for (int r = 0; r < 4; ++r) {
        const int row = bm + wr + i * 16 + lr4 + r;
        unsigned short* cp = &qbf[(size_t)row * D_EMB + bn + wc + lc];
        #pragma unroll
        for (int j = 0; j < 4; ++j) cp[j * 16] = f2bf(acc[i][j][r] + bv[j]);
      }
  } else {
    #pragma unroll
    for (int i = 0; i < 4; ++i) {
      const int row0 = bm + wr + i * 16 + lr4;
      const int n = row0 >> 11;
      const int jseq = row0 & (L_SEQ - 1);
      #pragma unroll
      for (int j = 0; j < 4; ++j) {
        const int cv = (bn - D_EMB) + wc + j * 16 + lc;
        const int d = cv & 63;
        const int h = cv >> 6;
        ushort4 o;
        o.x = f2bf(acc[i][j][0] + bv[j]);
        o.y = f2bf(acc[i][j][1] + bv[j]);
        o.z = f2bf(acc[i][j][2] + bv[j]);
        o.w = f2bf(acc[i][j][3] + bv[j]);
        *(ushort4*)&vT[(size_t)((n * 16 + h) * 64 + d) * L_SEQ + jseq] = o;
      }
    }
  }
}

// ---------------- out GEMM, 64x128 tile (1024 blocks = 4/CU), fp32 out ----------------
__global__ __launch_bounds__(256) void gemm_out64(
    const unsigned short* __restrict__ A, const unsigned short* __restrict__ B,
    const float* __restrict__ bias, float* __restrict__ C,
    int M, int Nn, int K) {
  __shared__ unsigned short As[2048];   // 64x32
  __shared__ unsigned short Bs[4096];   // 128x32
  const int bm = blockIdx.y * 64;
  const int bn = blockIdx.x * 128;
  const int tid = threadIdx.x;
  const int lane = tid & 63;
  const int wave = tid >> 6;
  const int wr = (wave >> 1) * 32;
  const int wc = (wave & 1) * 64;

  const int ca = tid;
  const int cb0 = tid, cb1 = tid + 256;
  const unsigned short* ga = A + (size_t)(bm + (ca >> 6) * 16 + (ca & 15)) * K + ((ca >> 4) & 3) * 8;
  const unsigned short* gb0 = B + (size_t)(bn + (cb0 >> 6) * 16 + (cb0 & 15)) * K + ((cb0 >> 4) & 3) * 8;
  const unsigned short* gb1 = B + (size_t)(bn + (cb1 >> 6) * 16 + (cb1 & 15)) * K + ((cb1 >> 4) & 3) * 8;

  f32x4 acc[2][4] = {};
  for (int k0 = 0; k0 < K; k0 += 32) {
    load16_to_lds(ga + k0, &As[ca * 8]);
    load16_to_lds(gb0 + k0, &Bs[cb0 * 8]);
    load16_to_lds(gb1 + k0, &Bs[cb1 * 8]);
    __syncthreads();
    bf16x8 af[2], bf[4];
    #pragma unroll
    for (int i = 0; i < 2; ++i)
      af[i] = *(const bf16x8*)&As[((wr >> 4) + i) * 512 + lane * 8];
    #pragma unroll
    for (int j = 0; j < 4; ++j)
      bf[j] = *(const bf16x8*)&Bs[((wc >> 4) + j) * 512 + lane * 8];
    #pragma unroll
    for (int i = 0; i < 2; ++i)
      #pragma unroll
      for (int j = 0; j < 4; ++j)
        acc[i][j] = __builtin_amdgcn_mfma_f32_16x16x32_bf16(af[i], bf[j], acc[i][j], 0, 0, 0);
    __syncthreads();
  }
  const int lc = lane & 15;
  const int lr4 = (lane >> 4) << 2;
  float bv[4];
  #pragma unroll
  for (int j = 0; j < 4; ++j) bv[j] = bias[bn + wc + j * 16 + lc];
  #pragma unroll
  for (int i = 0; i < 2; ++i)
    #pragma unroll
    for (int r = 0; r < 4; ++r) {
      const int row = bm + wr + i * 16 + lr4 + r;
      float* cp = &C[(size_t)row * Nn + bn + wc + lc];
      #pragma unroll
      for (int j = 0; j < 4; ++j) cp[j * 16] = acc[i][j][r] + bv[j];
    }
}

// ------------- qtemp (MFMA), 128-row chunks; writes per-chunk partials (no atomics) -------------
__global__ __launch_bounds__(256) void qtemp_mfma_kernel(
    const unsigned short* __restrict__ q_bf, const unsigned short* __restrict__ Wc_bf,
    const float* __restrict__ bc, const float* __restrict__ gamma,
    const float* __restrict__ beta, float* __restrict__ q_rel_part) {
  __shared__ unsigned short Qs[8192];   // 128 x 64 bf16, fragment-major
  __shared__ unsigned short Ws[4096];   // 64 x 64
  __shared__ float red[4][64];
  const int b = blockIdx.y;
  const int n = b >> 4, h = b & 15;
  const int l0 = blockIdx.x * 128;
  const int tid = threadIdx.x;
  const int lane = tid & 63;
  const int wave = tid >> 6;
  const int quad = lane >> 4;
  const int mi = lane & 15;

  #pragma unroll
  for (int s = 0; s < 4; ++s) {
    const int c = tid + s * 256;
    const int row = ((c >> 7) << 4) + (c & 15);
    const int kof = ((c >> 4) & 7) << 3;
    load16_to_lds(q_bf + (size_t)(n * L_SEQ + l0 + row) * D_EMB + h * 64 + kof,
                  &Qs[c * 8]);
  }
  #pragma unroll
  for (int s = 0; s < 2; ++s) {
    const int c = tid + s * 256;
    const int row = ((c >> 7) << 4) + (c & 15);
    const int kof = ((c >> 4) & 7) << 3;
    load16_to_lds(Wc_bf + row * 64 + kof, &Ws[c * 8]);
  }
  __syncthreads();

  f32x4 acc[2][4] = {};
  #pragma unroll
  for (int kk = 0; kk < 2; ++kk) {
    const int fo = ((kk * 4 + quad) * 16 + mi) * 8;
    bf16x8 bf[4];
    #pragma unroll
    for (int t = 0; t < 4; ++t) bf[t] = *(const bf16x8*)&Ws[t * 1024 + fo];
    #pragma unroll
    for (int isub = 0; isub < 2; ++isub) {
      const bf16x8 af = *(const bf16x8*)&Qs[(wave * 2 + isub) * 1024 + fo];
      #pragma unroll
      for (int t = 0; t < 4; ++t)
        acc[isub][t] = __builtin_amdgcn_mfma_f32_16x16x32_bf16(af, bf[t], acc[isub][t], 0, 0, 0);
    }
  }

  float bcv[4], gav[4], bev[4], colacc[4];
  #pragma unroll
  for (int t = 0; t < 4; ++t) {
    const int col = t * 16 + mi;
    bcv[t] = bc[col]; gav[t] = gamma[col]; bev[t] = beta[col];
    colacc[t] = 0.f;
  }
  #pragma unroll
  for (int isub = 0; isub < 2; ++isub) {
    #pragma unroll
    for (int r = 0; r < 4; ++r) {
      float g[4];
      float s1 = 0.f, s2 = 0.f;
      #pragma unroll
      for (int t = 0; t < 4; ++t) {
        const float d = acc[isub][t][r] + bcv[t];
        const float gg = 0.5f * d * (1.f + erff(d * 0.70710678118654752f));
        g[t] = gg;
        s1 += gg;
        s2 += gg * gg;
      }
      #pragma unroll
      for (int off = 8; off > 0; off >>= 1) {
        s1 += __shfl_xor(s1, off);
        s2 += __shfl_xor(s2, off);
      }
      const float mu = s1 * (1.f / 64.f);
      const float var = s2 * (1.f / 64.f) - mu * mu;
      const float rs = rsqrtf(var + LN_EPS);
      #pragma unroll
      for (int t = 0; t < 4; ++t)
        colacc[t] += (g[t] - mu) * rs * gav[t] + bev[t];
    }
  }
  #pragma unroll
  for (int t = 0; t < 4; ++t) {
    colacc[t] += __shfl_xor(colacc[t], 16);
    colacc[t] += __shfl_xor(colacc[t], 32);
  }
  if (quad == 0) {
    #pragma unroll
    for (int t = 0; t < 4; ++t) red[wave][t * 16 + mi] = colacc[t];
  }
  __syncthreads();
  if (wave == 0) {
    float tot = red[0][lane] + red[1][lane] + red[2][lane] + red[3][lane];
    q_rel_part[((size_t)b * 16 + blockIdx.x) * 64 + lane] = tot;
  }
}

// ------------- zw: q_rel reduce -> z = (S/L) q_rel @ Wk -> w_row = z.x + kb -------------
// grid (BHEADS, 8 t-chunks). k is never materialized.
__global__ __launch_bounds__(256) void zw_kernel(
    const float* __restrict__ part, const unsigned short* __restrict__ Win_bf,
    const float* __restrict__ b_in, const unsigned short* __restrict__ x_bf,
    float* __restrict__ w_row) {
  const int b = blockIdx.x;
  const int n = b >> 4, h = b & 15;
  const int tid = threadIdx.x;
  __shared__ float qrel[64];
  __shared__ float zsh[1024];
  __shared__ float ts[64];
  __shared__ float kbs;
  if (tid < 64) {
    float s = 0.f;
    #pragma unroll
    for (int c = 0; c < 16; ++c) s += part[((size_t)b * 16 + c) * 64 + tid];
    qrel[tid] = s;
    ts[tid] = s * b_in[D_EMB + h * 64 + tid];
  }
  __syncthreads();
  if (tid == 0) {
    float kb = 0.f;
    #pragma unroll
    for (int d = 0; d < 64; ++d) kb += ts[d];
    kbs = kb * (SCALING / (float)L_SEQ);
  }
  // z: 4 cols/thread over Wk rows (W_in rows 1024+h*64 .. +63)
  {
    const int j0 = tid * 4;
    float4 z4 = make_float4(0.f, 0.f, 0.f, 0.f);
    const unsigned short* wp = Win_bf + (size_t)(D_EMB + h * 64) * D_EMB + j0;
    #pragma unroll 4
    for (int d = 0; d < 64; ++d) {
      ushort4 w4 = *(const ushort4*)(wp + (size_t)d * D_EMB);
      const float qd = qrel[d];
      z4.x += qd * bf2f(w4.x);
      z4.y += qd * bf2f(w4.y);
      z4.z += qd * bf2f(w4.z);
      z4.w += qd * bf2f(w4.w);
    }
    const float sc = SCALING / (float)L_SEQ;
    zsh[j0 + 0] = z4.x * sc;
    zsh[j0 + 1] = z4.y * sc;
    zsh[j0 + 2] = z4.z * sc;
    zsh[j0 + 3] = z4.w * sc;
  }
  __syncthreads();
  const int t = blockIdx.y * 256 + tid;
  const unsigned short* xr = x_bf + (size_t)(n * L_SEQ + t) * D_EMB;
  float acc = kbs;
  #pragma unroll 4
  for (int c = 0; c < D_EMB; c += 8) {
    float4 zl = *(const float4*)&zsh[c];
    float4 zh = *(const float4*)&zsh[c + 4];
    uint4 xv = *(const uint4*)&xr[c];
    acc += zl.x * bflo(xv.x) + zl.y * bfhi(xv.x)
         + zl.z * bflo(xv.y) + zl.w * bfhi(xv.y)
         + zh.x * bflo(xv.z) + zh.y * bfhi(xv.z)
         + zh.z * bflo(xv.w) + zh.w * bfhi(xv.w);
  }
  w_row[b * L_SEQ + t] = acc;
}

// ------------- e[t]=exp(w[t]-max); inv[i]=1/prefix_sum(e) -------------
__global__ __launch_bounds__(256) void scan_kernel(
    const float* __restrict__ w_row, float* __restrict__ e_out,
    float* __restrict__ inv_out) {
  const int b = blockIdx.x;
  const int tid = threadIdx.x;
  __shared__ float sh[L_SEQ];
  __shared__ float ts[256];
  const float* wb = w_row + b * L_SEQ;
  float m = -3.4e38f;
  for (int i = tid; i < L_SEQ; i += 256) {
    float v = wb[i];
    sh[i] = v;
    m = fmaxf(m, v);
  }
  ts[tid] = m;
  __syncthreads();
  for (int off = 128; off > 0; off >>= 1) {
    if (tid < off) ts[tid] = fmaxf(ts[tid], ts[tid + off]);
    __syncthreads();
  }
  const float mx = ts[0];
  __syncthreads();
  const int t0 = tid * 8;
  float loc[8];
  float run = 0.f;
  #pragma unroll
  for (int k = 0; k < 8; ++k) {
    float ev = expf(sh[t0 + k] - mx);
    e_out[b * L_SEQ + t0 + k] = ev;
    run += ev;
    loc[k] = run;
  }
  ts[tid] = run;
  __syncthreads();
  for (int off = 1; off < 256; off <<= 1) {
    float v = ts[tid];
    float add = (tid >= off) ? ts[tid - off] : 0.f;
    __syncthreads();
    ts[tid] = v + add;
    __syncthreads();
  }
  float prefix = (tid > 0) ? ts[tid - 1] : 0.f;
  #pragma unroll
  for (int k = 0; k < 8; ++k)
    inv_out[b * L_SEQ + t0 + k] = 1.f / (prefix + loc[k]);
}

// ------------- causal Toeplitz conv via MFMA, d-split x2 (512 blocks) -------------
__global__ __launch_bounds__(256) void conv_mfma_kernel(
    const unsigned short* __restrict__ vT, const float* __restrict__ e_arr,
    const float* __restrict__ inv_arr, unsigned short* __restrict__ attn_out) {
  __shared__ unsigned short V_s[2][2048];
  __shared__ unsigned short rep[2][8 * 320];
  const int blk = 7 - blockIdx.x;
  const int b = blockIdx.y;
  const int dh = blockIdx.z;
  const int n = b >> 4, h = b & 15;
  const int blkI = blk * 256;
  const int blk4 = blk * 4;
  const int njt = blk4 + 4;
  const int tid = threadIdx.x;
  const int lane = tid & 63;
  const int wave = tid >> 6;
  const int quad = lane >> 4;
  const int mi = lane & 15;
  const float* e_b = e_arr + b * L_SEQ;

  const unsigned short* vsrc = vT +
      (size_t)(b * 64 + dh * 32 + (tid >> 7) * 16 + (tid & 15)) * L_SEQ + ((tid >> 4) & 7) * 8;

  f32x4 acc[4][2] = {};

  {
    load16_to_lds(vsrc, &V_s[0][tid * 8]);
    const int lagBase = blkI;
    int v = tid;
    int lag = lagBase + 256 - v;
    float ev = (lag >= 0 && lag < L_SEQ) ? e_b[lag] : 0.f;
    unsigned short bfv = f2bf(ev);
    #pragma unroll
    for (int r = 0; r < 8; ++r) { int idx = v - r; if (idx >= 0) rep[0][r * 320 + idx] = bfv; }
    if (tid < 64) {
      v = tid + 256;
      lag = lagBase - tid;
      ev = (lag >= 0 && lag < L_SEQ) ? e_b[lag] : 0.f;
      bfv = f2bf(ev);
      #pragma unroll
      for (int r = 0; r < 8; ++r) rep[0][r * 320 + (v - r)] = bfv;
    }
  }

  for (int jt = 0; jt < njt; ++jt) {
    __syncthreads();
    const int cb = jt & 1;
    if (jt + 1 < njt) {
      const int pb = cb ^ 1;
      const int j0 = (jt + 1) * 64;
      load16_to_lds(vsrc + j0, &V_s[pb][tid * 8]);
      const int lagBase = blkI - j0;
      int v = tid;
      int lag = lagBase + 256 - v;
      float ev = (lag >= 0 && lag < L_SEQ) ? e_b[lag] : 0.f;
      unsigned short bfv = f2bf(ev);
      #pragma unroll
      for (int r = 0; r < 8; ++r) { int idx = v - r; if (idx >= 0) rep[pb][r * 320 + idx] = bfv; }
      if (tid < 64) {
        v = tid + 256;
        lag = lagBase - tid;
        ev = (lag >= 0 && lag < L_SEQ) ? e_b[lag] : 0.f;
        bfv = f2bf(ev);
        #pragma unroll
        for (int r = 0; r < 8; ++r) rep[pb][r * 320 + (v - r)] = bfv;
      }
    }
    if (jt <= blk4 + wave) {
      const unsigned short* Vb = V_s[cb];
      const unsigned short* Rb = rep[cb];
      bf16x8 ef[6];
      #pragma unroll
      for (int q = 0; q < 6; ++q) {
        const int s = 256 - wave * 64 - mi + quad * 8 - 16 * (q - 2);
        const int rr = s & 7;
        ef[q] = *(const bf16x8*)&Rb[rr * 320 + (s - rr)];
      }
      #pragma unroll
      for (int kk = 0; kk < 2; ++kk) {
        bf16x8 bv[2];
        #pragma unroll
        for (int t = 0; t < 2; ++t)
          bv[t] = *(const bf16x8*)&Vb[t * 1024 + kk * 512 + lane * 8];
        #pragma unroll
        for (int isub = 0; isub < 4; ++isub) {
          const int qi = isub - 2 * kk + 2;
          #pragma unroll
          for (int t = 0; t < 2; ++t)
            acc[isub][t] = __builtin_amdgcn_mfma_f32_16x16x32_bf16(ef[qi], bv[t], acc[isub][t], 0, 0, 0);
        }
      }
    }
  }
  #pragma unroll
  for (int isub = 0; isub < 4; ++isub) {
    #pragma unroll
    for (int r = 0; r < 4; ++r) {
      const int i = blkI + wave * 64 + isub * 16 + quad * 4 + r;
      const float iv = inv_arr[b * L_SEQ + i];
      unsigned short* op = &attn_out[((size_t)(n * L_SEQ + i)) * D_EMB + h * 64 + dh * 32 + mi];
      #pragma unroll
      for (int t = 0; t < 2; ++t) op[t * 16] = f2bf(acc[isub][t][r] * iv);
    }
  }
}

// ------------- wm[b,j] = (1/L) * sum_{d>=0, j+d<L} e[d]*inv[j+d] -------------
__global__ __launch_bounds__(256) void wmean_kernel(
    const float* __restrict__ e_arr, const float* __restrict__ inv_arr,
    float* __restrict__ out_wm) {
  const int b = blockIdx.x;
  __shared__ float e_s[L_SEQ];
  __shared__ float inv_s[L_SEQ];
  __shared__ float red[256];
  const int tid = threadIdx.x;
  for (int i = tid; i < L_SEQ; i += 256) {
    e_s[i] = e_arr[b * L_SEQ + i];
    inv_s[i] = inv_arr[b * L_SEQ + i];
  }
  __syncthreads();
  const int jj = tid & 127;
  const int h2 = tid >> 7;
  const int j = blockIdx.y * 128 + jj;
  float acc = 0.f;
  for (int d = h2; j + d < L_SEQ; d += 2) acc += e_s[d] * inv_s[j + d];
  red[tid] = acc;
  __syncthreads();
  if (tid < 128)
    out_wm[b * L_SEQ + j] = (red[tid] + red[tid + 128]) * (1.f / (float)L_SEQ);
}

extern "C" void kernel_launch(void* const* d_in, const int* in_sizes, int n_in,
                              void* d_out, int out_size, void* d_ws, size_t ws_size,
                              hipStream_t stream) {
  const float* x       = (const float*)d_in[0];
  const float* W_in    = (const float*)d_in[1];
  const float* b_in    = (const float*)d_in[2];
  const float* Wc      = (const float*)d_in[3];
  const float* bc      = (const float*)d_in[4];
  const float* gamma   = (const float*)d_in[5];
  const float* beta    = (const float*)d_in[6];
  const float* W_out   = (const float*)d_in[7];
  const float* b_out   = (const float*)d_in[8];
  float* out = (float*)d_out;

  const int M = NBATCH * L_SEQ;      // 4096
  char* ws = (char*)d_ws;
  unsigned short* xa_bf  = (unsigned short*)ws;                 //  8,388,608 (x_bf, later attn_bf)
  unsigned short* Win_bf = (unsigned short*)(ws + 8388608);     //  6,291,456
  unsigned short* Wout_bf= (unsigned short*)(ws + 14680064);    //  2,097,152
  unsigned short* Wc_bf  = (unsigned short*)(ws + 16777216);    //      8,192
  unsigned short* q_bf   = (unsigned short*)(ws + 16785408);    //  8,388,608
  unsigned short* vT     = (unsigned short*)(ws + 25174016);    //  8,388,608
  float* part  = (float*)(ws + 33562624);                       //    131,072
  float* w_row = (float*)(ws + 33693696);                       //    262,144
  float* e_arr = (float*)(ws + 33955840);                       //    262,144
  float* inv_a = (float*)(ws + 34217984);                       //    262,144

  // 0) one fused convert: x, W_in, W_out, Wc
  {
    const int na = M * D_EMB, nb = 3 * D_EMB * D_EMB, nc = D_EMB * D_EMB, nd = HD * HD;
    cvt4_bf16_kernel<<<dim3((na + nb + nc + nd) / 1024), 256, 0, stream>>>(
        x, na, W_in, nb, W_out, nc, Wc, nd, xa_bf, Win_bf, Wout_bf, Wc_bf);
  }
  // 1) q,v GEMM (k columns algebraically eliminated) -> q_bf + transposed vT
  gemm_qv<<<dim3(16, 32), 256, 0, stream>>>(xa_bf, Win_bf, b_in, q_bf, vT, D_EMB);
  // 2) q_temp -> per-chunk q_rel partials (no atomics, no memset)
  qtemp_mfma_kernel<<<dim3(16, BHEADS), 256, 0, stream>>>(
      q_bf, Wc_bf, bc, gamma, beta, part);
  // 3) z = (S/L) q_rel@Wk; w_row = z.x + q_rel.bk
  zw_kernel<<<dim3(BHEADS, 8), 256, 0, stream>>>(part, Win_bf, b_in, xa_bf, w_row);
  // 4) softmax scan
  scan_kernel<<<dim3(BHEADS), 256, 0, stream>>>(w_row, e_arr, inv_a);
  // 5) weights.mean -> second output
  wmean_kernel<<<dim3(BHEADS, L_SEQ / 128), 256, 0, stream>>>(
      e_arr, inv_a, out + (size_t)M * D_EMB);
  // 6) causal Toeplitz conv via MFMA -> attn bf16 (overwrites x_bf region)
  conv_mfma_kernel<<<dim3(8, BHEADS, 2), 256, 0, stream>>>(vT, e_arr, inv_a, xa_bf);
  // 7) output = attn @ W_out^T + b_out
  gemm_out64<<<dim3(D_EMB / 128, M / 64), 256, 0, stream>>>(
      xa_bf, Wout_bf, b_out, out, M, D_EMB, D_EMB);
}

// Round 9
// 267.987 us; speedup vs baseline: 1.0587x; 1.0587x over previous
//
#include <hip/hip_runtime.h>
#include <math.h>

#define L_SEQ 2048
#define D_EMB 1024
#define NHEADS 16
#define HD 64
#define BHEADS 32   // N*NHEADS
#define NBATCH 2
#define LN_EPS 1e-5f
#define SCALING 0.125f
#define EREP_STRIDE 2304

typedef __attribute__((ext_vector_type(8))) __bf16 bf16x8;
typedef __attribute__((ext_vector_type(4))) float f32x4;
typedef const __attribute__((address_space(1))) unsigned int* gptr_as1;
typedef __attribute__((address_space(3))) unsigned int* lptr_as3;

__device__ __forceinline__ void load16_to_lds(const void* g, void* l) {
  __builtin_amdgcn_global_load_lds((gptr_as1)g, (lptr_as3)l, 16, 0, 0);
}

__device__ __forceinline__ unsigned short f2bf(float f) {
  unsigned int u = __float_as_uint(f);
  u += 0x7fff + ((u >> 16) & 1);   // round-to-nearest-even
  return (unsigned short)(u >> 16);
}

__device__ __forceinline__ float bflo(unsigned int u) { return __uint_as_float(u << 16); }
__device__ __forceinline__ float bfhi(unsigned int u) { return __uint_as_float(u & 0xffff0000u); }
__device__ __forceinline__ float bf2f(unsigned short us) {
  return __uint_as_float((unsigned int)us << 16);
}

// ---------------- four-tensor fp32 -> bf16 convert ----------------
__global__ __launch_bounds__(256) void cvt4_bf16_kernel(
    const float* __restrict__ a, int na, const float* __restrict__ b, int nb,
    const float* __restrict__ c, int nc, const float* __restrict__ d, int nd,
    unsigned short* __restrict__ oa, unsigned short* __restrict__ ob,
    unsigned short* __restrict__ oc, unsigned short* __restrict__ od) {
  int i = (blockIdx.x * 256 + threadIdx.x) * 4;
  const float* src;
  unsigned short* dst;
  int j;
  if (i < na) { src = a; dst = oa; j = i; }
  else if (i < na + nb) { src = b; dst = ob; j = i - na; }
  else if (i < na + nb + nc) { src = c; dst = oc; j = i - na - nb; }
  else if (i < na + nb + nc + nd) { src = d; dst = od; j = i - na - nb - nc; }
  else return;
  float4 v = *(const float4*)&src[j];
  ushort4 o;
  o.x = f2bf(v.x); o.y = f2bf(v.y); o.z = f2bf(v.z); o.w = f2bf(v.w);
  *(ushort4*)&dst[j] = o;
}

// ---------------- q+v GEMM (k columns skipped), 128x128, BK=32 ----------------
__global__ __launch_bounds__(256) void gemm_qv(
    const unsigned short* __restrict__ A, const unsigned short* __restrict__ B,
    const float* __restrict__ bias, unsigned short* __restrict__ qbf,
    unsigned short* __restrict__ vT, int K) {
  __shared__ unsigned short As[4096];
  __shared__ unsigned short Bs[4096];
  const int id = blockIdx.y * 16 + blockIdx.x;    // grid (16, 32)
  const int by = (id >> 5) * 2 + (id & 1);
  const int bx = (id & 31) >> 1;
  const int bm = by * 128;
  const int bn = bx * 128;
  const int woff = (bn < D_EMB) ? 0 : D_EMB;
  const int tid = threadIdx.x;
  const int lane = tid & 63;
  const int wave = tid >> 6;
  const int wr = (wave >> 1) * 64;
  const int wc = (wave & 1) * 64;

  const int c0 = tid, c1 = tid + 256;
  const unsigned short* ga0 = A + (size_t)(bm + (c0 >> 6) * 16 + (c0 & 15)) * K + ((c0 >> 4) & 3) * 8;
  const unsigned short* ga1 = A + (size_t)(bm + (c1 >> 6) * 16 + (c1 & 15)) * K + ((c1 >> 4) & 3) * 8;
  const unsigned short* gb0 = B + (size_t)(bn + woff + (c0 >> 6) * 16 + (c0 & 15)) * K + ((c0 >> 4) & 3) * 8;
  const unsigned short* gb1 = B + (size_t)(bn + woff + (c1 >> 6) * 16 + (c1 & 15)) * K + ((c1 >> 4) & 3) * 8;

  f32x4 acc[4][4] = {};
  for (int k0 = 0; k0 < K; k0 += 32) {
    load16_to_lds(ga0 + k0, &As[c0 * 8]);
    load16_to_lds(ga1 + k0, &As[c1 * 8]);
    load16_to_lds(gb0 + k0, &Bs[c0 * 8]);
    load16_to_lds(gb1 + k0, &Bs[c1 * 8]);
    __syncthreads();
    bf16x8 af[4], bf[4];
    #pragma unroll
    for (int i = 0; i < 4; ++i)
      af[i] = *(const bf16x8*)&As[((wr >> 4) + i) * 512 + lane * 8];
    #pragma unroll
    for (int j = 0; j < 4; ++j)
      bf[j] = *(const bf16x8*)&Bs[((wc >> 4) + j) * 512 + lane * 8];
    #pragma unroll
    for (int i = 0; i < 4; ++i)
      #pragma unroll
      for (int j = 0; j < 4; ++j)
        acc[i][j] = __builtin_amdgcn_mfma_f32_16x16x32_bf16(af[i], bf[j], acc[i][j], 0, 0, 0);
    __syncthreads();
  }
  const int lc = lane & 15;
  const int lr4 = (lane >> 4) << 2;
  float bv[4];
  #pragma unroll
  for (int j = 0; j < 4; ++j) bv[j] = bias[bn + woff + wc + j * 16 + lc];
  if (bn < D_EMB) {
    #pragma unroll
    for (int i = 0; i < 4; ++i)
      #pragma unroll
      for (int r = 0; r < 4; ++r) {
        const int row = bm + wr + i * 16 + lr4 + r;
        unsigned short* cp = &qbf[(size_t)row * D_EMB + bn + wc + lc];
        #pragma unroll
        for (int j = 0; j < 4; ++j) cp[j * 16] = f2bf(acc[i][j][r] + bv[j]);
      }
  } else {
    #pragma unroll
    for (int i = 0; i < 4; ++i) {
      const int row0 = bm + wr + i * 16 + lr4;
      const int n = row0 >> 11;
      const int jseq = row0 & (L_SEQ - 1);
      #pragma unroll
      for (int j = 0; j < 4; ++j) {
        const int cv = (bn - D_EMB) + wc + j * 16 + lc;
        const int d = cv & 63;
        const int h = cv >> 6;
        ushort4 o;
        o.x = f2bf(acc[i][j][0] + bv[j]);
        o.y = f2bf(acc[i][j][1] + bv[j]);
        o.z = f2bf(acc[i][j][2] + bv[j]);
        o.w = f2bf(acc[i][j][3] + bv[j]);
        *(ushort4*)&vT[(size_t)((n * 16 + h) * 64 + d) * L_SEQ + jseq] = o;
      }
    }
  }
}

// ---------------- out GEMM, 64x128 tile, fp32 out ----------------
__global__ __launch_bounds__(256) void gemm_out64(
    const unsigned short* __restrict__ A, const unsigned short* __restrict__ B,
    const float* __restrict__ bias, float* __restrict__ C,
    int M, int Nn, int K) {
  __shared__ unsigned short As[2048];
  __shared__ unsigned short Bs[4096];
  const int bm = blockIdx.y * 64;
  const int bn = blockIdx.x * 128;
  const int tid = threadIdx.x;
  const int lane = tid & 63;
  const int wave = tid >> 6;
  const int wr = (wave >> 1) * 32;
  const int wc = (wave & 1) * 64;

  const int ca = tid;
  const int cb0 = tid, cb1 = tid + 256;
  const unsigned short* ga = A + (size_t)(bm + (ca >> 6) * 16 + (ca & 15)) * K + ((ca >> 4) & 3) * 8;
  const unsigned short* gb0 = B + (size_t)(bn + (cb0 >> 6) * 16 + (cb0 & 15)) * K + ((cb0 >> 4) & 3) * 8;
  const unsigned short* gb1 = B + (size_t)(bn + (cb1 >> 6) * 16 + (cb1 & 15)) * K + ((cb1 >> 4) & 3) * 8;

  f32x4 acc[2][4] = {};
  for (int k0 = 0; k0 < K; k0 += 32) {
    load16_to_lds(ga + k0, &As[ca * 8]);
    load16_to_lds(gb0 + k0, &Bs[cb0 * 8]);
    load16_to_lds(gb1 + k0, &Bs[cb1 * 8]);
    __syncthreads();
    bf16x8 af[2], bf[4];
    #pragma unroll
    for (int i = 0; i < 2; ++i)
      af[i] = *(const bf16x8*)&As[((wr >> 4) + i) * 512 + lane * 8];
    #pragma unroll
    for (int j = 0; j < 4; ++j)
      bf[j] = *(const bf16x8*)&Bs[((wc >> 4) + j) * 512 + lane * 8];
    #pragma unroll
    for (int i = 0; i < 2; ++i)
      #pragma unroll
      for (int j = 0; j < 4; ++j)
        acc[i][j] = __builtin_amdgcn_mfma_f32_16x16x32_bf16(af[i], bf[j], acc[i][j], 0, 0, 0);
    __syncthreads();
  }
  const int lc = lane & 15;
  const int lr4 = (lane >> 4) << 2;
  float bv[4];
  #pragma unroll
  for (int j = 0; j < 4; ++j) bv[j] = bias[bn + wc + j * 16 + lc];
  #pragma unroll
  for (int i = 0; i < 2; ++i)
    #pragma unroll
    for (int r = 0; r < 4; ++r) {
      const int row = bm + wr + i * 16 + lr4 + r;
      float* cp = &C[(size_t)row * Nn + bn + wc + lc];
      #pragma unroll
      for (int j = 0; j < 4; ++j) cp[j * 16] = acc[i][j][r] + bv[j];
    }
}

// ------------- qtemp (MFMA), 128-row chunks; per-chunk partials -------------
__global__ __launch_bounds__(256) void qtemp_mfma_kernel(
    const unsigned short* __restrict__ q_bf, const unsigned short* __restrict__ Wc_bf,
    const float* __restrict__ bc, const float* __restrict__ gamma,
    const float* __restrict__ beta, float* __restrict__ q_rel_part) {
  __shared__ unsigned short Qs[8192];
  __shared__ unsigned short Ws[4096];
  __shared__ float red[4][64];
  const int b = blockIdx.y;
  const int n = b >> 4, h = b & 15;
  const int l0 = blockIdx.x * 128;
  const int tid = threadIdx.x;
  const int lane = tid & 63;
  const int wave = tid >> 6;
  const int quad = lane >> 4;
  const int mi = lane & 15;

  #pragma unroll
  for (int s = 0; s < 4; ++s) {
    const int c = tid + s * 256;
    const int row = ((c >> 7) << 4) + (c & 15);
    const int kof = ((c >> 4) & 7) << 3;
    load16_to_lds(q_bf + (size_t)(n * L_SEQ + l0 + row) * D_EMB + h * 64 + kof,
                  &Qs[c * 8]);
  }
  #pragma unroll
  for (int s = 0; s < 2; ++s) {
    const int c = tid + s * 256;
    const int row = ((c >> 7) << 4) + (c & 15);
    const int kof = ((c >> 4) & 7) << 3;
    load16_to_lds(Wc_bf + row * 64 + kof, &Ws[c * 8]);
  }
  __syncthreads();

  f32x4 acc[2][4] = {};
  #pragma unroll
  for (int kk = 0; kk < 2; ++kk) {
    const int fo = ((kk * 4 + quad) * 16 + mi) * 8;
    bf16x8 bf[4];
    #pragma unroll
    for (int t = 0; t < 4; ++t) bf[t] = *(const bf16x8*)&Ws[t * 1024 + fo];
    #pragma unroll
    for (int isub = 0; isub < 2; ++isub) {
      const bf16x8 af = *(const bf16x8*)&Qs[(wave * 2 + isub) * 1024 + fo];
      #pragma unroll
      for (int t = 0; t < 4; ++t)
        acc[isub][t] = __builtin_amdgcn_mfma_f32_16x16x32_bf16(af, bf[t], acc[isub][t], 0, 0, 0);
    }
  }

  float bcv[4], gav[4], bev[4], colacc[4];
  #pragma unroll
  for (int t = 0; t < 4; ++t) {
    const int col = t * 16 + mi;
    bcv[t] = bc[col]; gav[t] = gamma[col]; bev[t] = beta[col];
    colacc[t] = 0.f;
  }
  #pragma unroll
  for (int isub = 0; isub < 2; ++isub) {
    #pragma unroll
    for (int r = 0; r < 4; ++r) {
      float g[4];
      float s1 = 0.f, s2 = 0.f;
      #pragma unroll
      for (int t = 0; t < 4; ++t) {
        const float d = acc[isub][t][r] + bcv[t];
        const float gg = 0.5f * d * (1.f + erff(d * 0.70710678118654752f));
        g[t] = gg;
        s1 += gg;
        s2 += gg * gg;
      }
      #pragma unroll
      for (int off = 8; off > 0; off >>= 1) {
        s1 += __shfl_xor(s1, off);
        s2 += __shfl_xor(s2, off);
      }
      const float mu = s1 * (1.f / 64.f);
      const float var = s2 * (1.f / 64.f) - mu * mu;
      const float rs = rsqrtf(var + LN_EPS);
      #pragma unroll
      for (int t = 0; t < 4; ++t)
        colacc[t] += (g[t] - mu) * rs * gav[t] + bev[t];
    }
  }
  #pragma unroll
  for (int t = 0; t < 4; ++t) {
    colacc[t] += __shfl_xor(colacc[t], 16);
    colacc[t] += __shfl_xor(colacc[t], 32);
  }
  if (quad == 0) {
    #pragma unroll
    for (int t = 0; t < 4; ++t) red[wave][t * 16 + mi] = colacc[t];
  }
  __syncthreads();
  if (wave == 0) {
    float tot = red[0][lane] + red[1][lane] + red[2][lane] + red[3][lane];
    q_rel_part[((size_t)b * 16 + blockIdx.x) * 64 + lane] = tot;
  }
}

// ------------- zw: q_rel reduce -> z = (S/L) q_rel @ Wk -> w_row = z.x + kb -------------
__global__ __launch_bounds__(256) void zw_kernel(
    const float* __restrict__ part, const unsigned short* __restrict__ Win_bf,
    const float* __restrict__ b_in, const unsigned short* __restrict__ x_bf,
    float* __restrict__ w_row) {
  const int b = blockIdx.x;
  const int n = b >> 4, h = b & 15;
  const int tid = threadIdx.x;
  __shared__ float qrel[64];
  __shared__ float zsh[1024];
  __shared__ float ts[64];
  __shared__ float kbs;
  if (tid < 64) {
    float s = 0.f;
    #pragma unroll
    for (int c = 0; c < 16; ++c) s += part[((size_t)b * 16 + c) * 64 + tid];
    qrel[tid] = s;
    ts[tid] = s * b_in[D_EMB + h * 64 + tid];
  }
  __syncthreads();
  if (tid == 0) {
    float kb = 0.f;
    #pragma unroll
    for (int d = 0; d < 64; ++d) kb += ts[d];
    kbs = kb * (SCALING / (float)L_SEQ);
  }
  {
    const int j0 = tid * 4;
    float4 z4 = make_float4(0.f, 0.f, 0.f, 0.f);
    const unsigned short* wp = Win_bf + (size_t)(D_EMB + h * 64) * D_EMB + j0;
    #pragma unroll 4
    for (int d = 0; d < 64; ++d) {
      ushort4 w4 = *(const ushort4*)(wp + (size_t)d * D_EMB);
      const float qd = qrel[d];
      z4.x += qd * bf2f(w4.x);
      z4.y += qd * bf2f(w4.y);
      z4.z += qd * bf2f(w4.z);
      z4.w += qd * bf2f(w4.w);
    }
    const float sc = SCALING / (float)L_SEQ;
    zsh[j0 + 0] = z4.x * sc;
    zsh[j0 + 1] = z4.y * sc;
    zsh[j0 + 2] = z4.z * sc;
    zsh[j0 + 3] = z4.w * sc;
  }
  __syncthreads();
  const int t = blockIdx.y * 256 + tid;
  const unsigned short* xr = x_bf + (size_t)(n * L_SEQ + t) * D_EMB;
  float acc = kbs;
  #pragma unroll 4
  for (int c = 0; c < D_EMB; c += 8) {
    float4 zl = *(const float4*)&zsh[c];
    float4 zh = *(const float4*)&zsh[c + 4];
    uint4 xv = *(const uint4*)&xr[c];
    acc += zl.x * bflo(xv.x) + zl.y * bfhi(xv.x)
         + zl.z * bflo(xv.y) + zl.w * bfhi(xv.y)
         + zh.x * bflo(xv.z) + zh.y * bfhi(xv.z)
         + zh.z * bflo(xv.w) + zh.w * bfhi(xv.w);
  }
  w_row[b * L_SEQ + t] = acc;
}

// ------------- scan: e = exp(w - max); inv = 1/prefix; + write 8 reversed bf16 e-replicas -------------
// erep[(b*8+r)*2304 + x] = bf16(e[2047 - x - r]), 0 if index < 0.  A-frag in conv
// becomes ONE aligned 16B L2 load (replica r = (2047 - mi) & 7 is lane-constant).
__global__ __launch_bounds__(256) void scan_kernel(
    const float* __restrict__ w_row, float* __restrict__ e_out,
    float* __restrict__ inv_out, unsigned short* __restrict__ erep) {
  const int b = blockIdx.x;
  const int tid = threadIdx.x;
  __shared__ float sh[L_SEQ];
  __shared__ float ts[256];
  const float* wb = w_row + b * L_SEQ;
  float m = -3.4e38f;
  for (int i = tid; i < L_SEQ; i += 256) {
    float v = wb[i];
    sh[i] = v;
    m = fmaxf(m, v);
  }
  ts[tid] = m;
  __syncthreads();
  for (int off = 128; off > 0; off >>= 1) {
    if (tid < off) ts[tid] = fmaxf(ts[tid], ts[tid + off]);
    __syncthreads();
  }
  const float mx = ts[0];
  __syncthreads();
  const int t0 = tid * 8;
  float loc[8];
  float run = 0.f;
  #pragma unroll
  for (int k = 0; k < 8; ++k) {
    float ev = expf(sh[t0 + k] - mx);
    e_out[b * L_SEQ + t0 + k] = ev;
    sh[t0 + k] = ev;              // e now lives in sh
    run += ev;
    loc[k] = run;
  }
  ts[tid] = run;
  __syncthreads();
  for (int off = 1; off < 256; off <<= 1) {
    float v = ts[tid];
    float add = (tid >= off) ? ts[tid - off] : 0.f;
    __syncthreads();
    ts[tid] = v + add;
    __syncthreads();
  }
  float prefix = (tid > 0) ? ts[tid - 1] : 0.f;
  #pragma unroll
  for (int k = 0; k < 8; ++k)
    inv_out[b * L_SEQ + t0 + k] = 1.f / (prefix + loc[k]);
  // ---- e-replica writes (sh holds e; last barrier in scan loop synced it) ----
  for (int idx = tid; idx < 8 * (EREP_STRIDE / 4); idx += 256) {
    const int r = idx / (EREP_STRIDE / 4);
    const int x4 = (idx - r * (EREP_STRIDE / 4)) * 4;
    const int src = 2047 - x4 - r;
    ushort4 o;
    o.x = (src >= 0)     ? f2bf(sh[src])     : (unsigned short)0;
    o.y = (src - 1 >= 0) ? f2bf(sh[src - 1]) : (unsigned short)0;
    o.z = (src - 2 >= 0) ? f2bf(sh[src - 2]) : (unsigned short)0;
    o.w = (src - 3 >= 0) ? f2bf(sh[src - 3]) : (unsigned short)0;
    *(ushort4*)&erep[((size_t)b * 8 + r) * EREP_STRIDE + x4] = o;
  }
}

// ------------- causal Toeplitz conv via MFMA: 256-j tiles, global e-replica A-frags -------------
// grid (8 i-bands, 32 b, 2 d-halves). Wave w owns i rows [blkI + w*64, +64).
// Per 256-j tile: V staged (32d x 256j bf16, 16 KB, dbuf) via global_load_lds;
// A-frags = rolling window of one-aligned-16B L2 loads from erep. 64 MFMA/wave/tile.
__global__ __launch_bounds__(256) void conv_mfma_kernel(
    const unsigned short* __restrict__ vT, const unsigned short* __restrict__ erep,
    const float* __restrict__ inv_arr, unsigned short* __restrict__ attn_out) {
  __shared__ unsigned short V_s[2][8192];   // 2 x 16 KB
  const int blk = 7 - blockIdx.x;           // heavy blocks first
  const int b = blockIdx.y;
  const int dh = blockIdx.z;
  const int n = b >> 4, h = b & 15;
  const int blkI = blk * 256;
  const int ntiles = blk + 1;
  const int tid = threadIdx.x;
  const int lane = tid & 63;
  const int wave = tid >> 6;
  const int quad = lane >> 4;
  const int mi = lane & 15;

  // V staging: 4 chunks/thread; chunk c: dgrp=c>>9, jq=(c>>4)&31, mid=c&15
  const unsigned short* vsrc[4];
  #pragma unroll
  for (int s = 0; s < 4; ++s) {
    const int c = tid + s * 256;
    vsrc[s] = vT + (size_t)(b * 64 + dh * 32 + (c >> 9) * 16 + (c & 15)) * L_SEQ + ((c >> 4) & 31) * 8;
  }

  const int r = (2047 - mi) & 7;            // lane-constant replica index
  const unsigned short* eb = erep + ((size_t)b * 8 + r) * EREP_STRIDE;
  const int ub0 = 2047 - blkI - wave * 64 - mi + quad * 8 - r;   // aligned; add j0 + 16v

  f32x4 acc[4][2] = {};

  #pragma unroll
  for (int s = 0; s < 4; ++s) load16_to_lds(vsrc[s], &V_s[0][(tid + s * 256) * 8]);

  for (int jt = 0; jt < ntiles; ++jt) {
    __syncthreads();
    const int cb = jt & 1;
    if (jt + 1 < ntiles) {
      #pragma unroll
      for (int s = 0; s < 4; ++s)
        load16_to_lds(vsrc[s] + (jt + 1) * 256, &V_s[cb ^ 1][(tid + s * 256) * 8]);
    }
    const unsigned short* Vb = V_s[cb];
    const int ub = ub0 + jt * 256;
    // rolling A-frags: f_i holds F(2kk - i), F(v) at eb[ub + 16v]
    bf16x8 f0 = *(const bf16x8*)&eb[ub];
    bf16x8 f1 = *(const bf16x8*)&eb[ub - 16];
    bf16x8 f2 = *(const bf16x8*)&eb[ub - 32];
    bf16x8 f3 = *(const bf16x8*)&eb[ub - 48];
    #pragma unroll
    for (int kk = 0; kk < 8; ++kk) {
      const bf16x8 b0 = *(const bf16x8*)&Vb[(((kk * 4 + quad) * 16 + mi)) * 8];
      const bf16x8 b1 = *(const bf16x8*)&Vb[((512 + (kk * 4 + quad) * 16 + mi)) * 8];
      acc[0][0] = __builtin_amdgcn_mfma_f32_16x16x32_bf16(f0, b0, acc[0][0], 0, 0, 0);
      acc[0][1] = __builtin_amdgcn_mfma_f32_16x16x32_bf16(f0, b1, acc[0][1], 0, 0, 0);
      acc[1][0] = __builtin_amdgcn_mfma_f32_16x16x32_bf16(f1, b0, acc[1][0], 0, 0, 0);
      acc[1][1] = __builtin_amdgcn_mfma_f32_16x16x32_bf16(f1, b1, acc[1][1], 0, 0, 0);
      acc[2][0] = __builtin_amdgcn_mfma_f32_16x16x32_bf16(f2, b0, acc[2][0], 0, 0, 0);
      acc[2][1] = __builtin_amdgcn_mfma_f32_16x16x32_bf16(f2, b1, acc[2][1], 0, 0, 0);
      acc[3][0] = __builtin_amdgcn_mfma_f32_16x16x32_bf16(f3, b0, acc[3][0], 0, 0, 0);
      acc[3][1] = __builtin_amdgcn_mfma_f32_16x16x32_bf16(f3, b1, acc[3][1], 0, 0, 0);
      f2 = f0;
      f3 = f1;
      if (kk < 7) {
        f0 = *(const bf16x8*)&eb[ub + 32 * (kk + 1)];
        f1 = *(const bf16x8*)&eb[ub + 32 * kk + 16];
      }
    }
  }
  #pragma unroll
  for (int isub = 0; isub < 4; ++isub) {
    #pragma unroll
    for (int rr = 0; rr < 4; ++rr) {
      const int i = blkI + wave * 64 + isub * 16 + quad * 4 + rr;
      const float iv = inv_arr[b * L_SEQ + i];
      unsigned short* op = &attn_out[((size_t)(n * L_SEQ + i)) * D_EMB + h * 64 + dh * 32 + mi];
      #pragma unroll
      for (int t = 0; t < 2; ++t) op[t * 16] = f2bf(acc[isub][t][rr] * iv);
    }
  }
}

// ------------- wm[b,j] = (1/L) * sum e[d]*inv[j+d], 4-way d-split -------------
__global__ __launch_bounds__(256) void wmean_kernel(
    const float* __restrict__ e_arr, const float* __restrict__ inv_arr,
    float* __restrict__ out_wm) {
  const int b = blockIdx.x;
  __shared__ float e_s[L_SEQ];
  __shared__ float inv_s[L_SEQ];
  __shared__ float red[256];
  const int tid = threadIdx.x;
  for (int i = tid; i < L_SEQ; i += 256) {
    e_s[i] = e_arr[b * L_SEQ + i];
    inv_s[i] = inv_arr[b * L_SEQ + i];
  }
  __syncthreads();
  const int jj = tid & 63;
  const int ds = tid >> 6;          // 0..3
  const int j = blockIdx.y * 64 + jj;
  float acc = 0.f;
  for (int d = ds; j + d < L_SEQ; d += 4) acc += e_s[d] * inv_s[j + d];
  red[tid] = acc;
  __syncthreads();
  if (tid < 64)
    out_wm[b * L_SEQ + j] =
        (red[jj] + red[jj + 64] + red[jj + 128] + red[jj + 192]) * (1.f / (float)L_SEQ);
}

extern "C" void kernel_launch(void* const* d_in, const int* in_sizes, int n_in,
                              void* d_out, int out_size, void* d_ws, size_t ws_size,
                              hipStream_t stream) {
  const float* x       = (const float*)d_in[0];
  const float* W_in    = (const float*)d_in[1];
  const float* b_in    = (const float*)d_in[2];
  const float* Wc      = (const float*)d_in[3];
  const float* bc      = (const float*)d_in[4];
  const float* gamma   = (const float*)d_in[5];
  const float* beta    = (const float*)d_in[6];
  const float* W_out   = (const float*)d_in[7];
  const float* b_out   = (const float*)d_in[8];
  float* out = (float*)d_out;

  const int M = NBATCH * L_SEQ;      // 4096
  char* ws = (char*)d_ws;
  unsigned short* xa_bf  = (unsigned short*)ws;                 //  8,388,608 (x_bf, later attn_bf)
  unsigned short* Win_bf = (unsigned short*)(ws + 8388608);     //  6,291,456
  unsigned short* Wout_bf= (unsigned short*)(ws + 14680064);    //  2,097,152
  unsigned short* Wc_bf  = (unsigned short*)(ws + 16777216);    //      8,192
  unsigned short* q_bf   = (unsigned short*)(ws + 16785408);    //  8,388,608
  unsigned short* vT     = (unsigned short*)(ws + 25174016);    //  8,388,608
  float* part  = (float*)(ws + 33562624);                       //    131,072
  float* w_row = (float*)(ws + 33693696);                       //    262,144
  float* e_arr = (float*)(ws + 33955840);                       //    262,144
  float* inv_a = (float*)(ws + 34217984);                       //    262,144
  unsigned short* erep   = (unsigned short*)(ws + 34480128);    //  2,359,296

  // 0) one fused convert: x, W_in, W_out, Wc
  {
    const int na = M * D_EMB, nb = 3 * D_EMB * D_EMB, nc = D_EMB * D_EMB, nd = HD * HD;
    cvt4_bf16_kernel<<<dim3((na + nb + nc + nd) / 1024), 256, 0, stream>>>(
        x, na, W_in, nb, W_out, nc, Wc, nd, xa_bf, Win_bf, Wout_bf, Wc_bf);
  }
  // 1) q,v GEMM (k eliminated) -> q_bf + transposed vT
  gemm_qv<<<dim3(16, 32), 256, 0, stream>>>(xa_bf, Win_bf, b_in, q_bf, vT, D_EMB);
  // 2) q_temp -> per-chunk q_rel partials
  qtemp_mfma_kernel<<<dim3(16, BHEADS), 256, 0, stream>>>(
      q_bf, Wc_bf, bc, gamma, beta, part);
  // 3) z = (S/L) q_rel@Wk; w_row = z.x + q_rel.bk
  zw_kernel<<<dim3(BHEADS, 8), 256, 0, stream>>>(part, Win_bf, b_in, xa_bf, w_row);
  // 4) softmax scan + e-replica writes
  scan_kernel<<<dim3(BHEADS), 256, 0, stream>>>(w_row, e_arr, inv_a, erep);
  // 5) weights.mean -> second output
  wmean_kernel<<<dim3(BHEADS, L_SEQ / 64), 256, 0, stream>>>(
      e_arr, inv_a, out + (size_t)M * D_EMB);
  // 6) causal Toeplitz conv via MFMA (256-j tiles) -> attn bf16 (overwrites x_bf)
  conv_mfma_kernel<<<dim3(8, BHEADS, 2), 256, 0, stream>>>(vT, erep, inv_a, xa_bf);
  // 7) output = attn @ W_out^T + b_out
  gemm_out64<<<dim3(D_EMB / 128, M / 64), 256, 0, stream>>>(
      xa_bf, Wout_bf, b_out, out, M, D_EMB, D_EMB);
}